// Round 4
// baseline (146.776 us; speedup 1.0000x reference)
//
#include <hip/hip_runtime.h>

#define NTHREADS 256
#define NBLOCKS 2048   // 8 blocks/CU * 256 CUs -> 32/32 waves/CU (VGPR=20 allows 8 waves/SIMD)

typedef float f32x4 __attribute__((ext_vector_type(4)));  // native vec: nontemporal builtin accepts it

__device__ __forceinline__ float wave_reduce(float v) {
    #pragma unroll
    for (int off = 32; off > 0; off >>= 1) v += __shfl_down(v, off, 64);
    return v;
}

__device__ __forceinline__ float block_reduce(float v) {
    v = wave_reduce(v);
    __shared__ float smem[NTHREADS / 64];
    const int lane = threadIdx.x & 63;
    const int wave = threadIdx.x >> 6;
    if (lane == 0) smem[wave] = v;
    __syncthreads();
    float s = 0.f;
    if (threadIdx.x == 0) {
        #pragma unroll
        for (int w = 0; w < NTHREADS / 64; ++w) s += smem[w];
    }
    return s;
}

// Each "group" = 4 consecutive triples = 12 consecutive floats = 3 float4.
// A thread loads 3 float4 from pred + 3 from target. Loads are NON-TEMPORAL
// (global_load_dwordx4 ... nt): stream is touched exactly once, so cache
// allocation is pure overhead — theory: that path is the 3 TB/s cap.
__global__ __launch_bounds__(NTHREADS) void dis_partial_kernel(
    const f32x4* __restrict__ p4, const f32x4* __restrict__ t4,
    const float* __restrict__ pred, const float* __restrict__ targ,
    float* __restrict__ partials, int ngroup, int ntrip) {
    const int nth = gridDim.x * NTHREADS;
    float acc = 0.f;

    for (int g = blockIdx.x * NTHREADS + threadIdx.x; g < ngroup; g += nth) {
        const int b = 3 * g;
        const f32x4 pa = __builtin_nontemporal_load(&p4[b + 0]);
        const f32x4 pb = __builtin_nontemporal_load(&p4[b + 1]);
        const f32x4 pc = __builtin_nontemporal_load(&p4[b + 2]);
        const f32x4 qa = __builtin_nontemporal_load(&t4[b + 0]);
        const f32x4 qb = __builtin_nontemporal_load(&t4[b + 1]);
        const f32x4 qc = __builtin_nontemporal_load(&t4[b + 2]);

        const float d0  = pa.x - qa.x;
        const float d1  = pa.y - qa.y;
        const float d2  = pa.z - qa.z;
        const float d3  = pa.w - qa.w;
        const float d4  = pb.x - qb.x;
        const float d5  = pb.y - qb.y;
        const float d6  = pb.z - qb.z;
        const float d7  = pb.w - qb.w;
        const float d8  = pc.x - qc.x;
        const float d9  = pc.y - qc.y;
        const float d10 = pc.z - qc.z;
        const float d11 = pc.w - qc.w;

        acc += sqrtf(d0 * d0 + d1 * d1 + d2 * d2);
        acc += sqrtf(d3 * d3 + d4 * d4 + d5 * d5);
        acc += sqrtf(d6 * d6 + d7 * d7 + d8 * d8);
        acc += sqrtf(d9 * d9 + d10 * d10 + d11 * d11);
    }

    // Generic scalar tail (empty here: ntrip = 5,505,024 = 4 * 1,376,256).
    for (int j = ngroup * 4 + blockIdx.x * NTHREADS + threadIdx.x; j < ntrip;
         j += nth) {
        const float dx = pred[3 * j + 0] - targ[3 * j + 0];
        const float dy = pred[3 * j + 1] - targ[3 * j + 1];
        const float dz = pred[3 * j + 2] - targ[3 * j + 2];
        acc += sqrtf(dx * dx + dy * dy + dz * dz);
    }

    const float s = block_reduce(acc);
    if (threadIdx.x == 0) partials[blockIdx.x] = s;
}

__global__ __launch_bounds__(NTHREADS) void dis_finalize_kernel(
    const float* __restrict__ partials, float* __restrict__ out,
    int nblocks, float scale) {
    float acc = 0.f;
    for (int i = threadIdx.x; i < nblocks; i += NTHREADS) acc += partials[i];
    const float s = block_reduce(acc);
    if (threadIdx.x == 0) out[0] = s * scale;  // full overwrite of poisoned d_out
}

extern "C" void kernel_launch(void* const* d_in, const int* in_sizes, int n_in,
                              void* d_out, int out_size, void* d_ws, size_t ws_size,
                              hipStream_t stream) {
    const float* pred = (const float*)d_in[0];
    const float* targ = (const float*)d_in[1];
    float* out = (float*)d_out;
    float* partials = (float*)d_ws;  // NBLOCKS floats, each block owns its slot

    const int n = in_sizes[0];          // B * 63 = 16,515,072 floats
    const int ntrip = n / 3;            // 5,505,024 joint distances
    const int ngroup = ntrip / 4;       // 1,376,256 groups of 4 triples (exact)
    const float scale = 1.0f / (float)ntrip;

    dis_partial_kernel<<<NBLOCKS, NTHREADS, 0, stream>>>(
        (const f32x4*)pred, (const f32x4*)targ, pred, targ, partials, ngroup, ntrip);
    dis_finalize_kernel<<<1, NTHREADS, 0, stream>>>(partials, out, NBLOCKS, scale);
}

// Round 6
// 145.900 us; speedup vs baseline: 1.0060x; 1.0060x over previous
//
#include <hip/hip_runtime.h>

#define NTHREADS 256
#define NBLOCKS 1792   // 458,752 threads x 3 groups each = 1,376,256 groups EXACTLY

typedef float f32x4 __attribute__((ext_vector_type(4)));

__device__ __forceinline__ float wave_reduce(float v) {
    #pragma unroll
    for (int off = 32; off > 0; off >>= 1) v += __shfl_down(v, off, 64);
    return v;
}

__device__ __forceinline__ float block_reduce(float v) {
    v = wave_reduce(v);
    __shared__ float smem[NTHREADS / 64];
    const int lane = threadIdx.x & 63;
    const int wave = threadIdx.x >> 6;
    if (lane == 0) smem[wave] = v;
    __syncthreads();
    float s = 0.f;
    if (threadIdx.x == 0) {
        #pragma unroll
        for (int w = 0; w < NTHREADS / 64; ++w) s += smem[w];
    }
    return s;
}

// 4 triples from 3 pred-float4 + 3 targ-float4.
__device__ __forceinline__ float group_dist(const f32x4 pa, const f32x4 pb,
                                            const f32x4 pc, const f32x4 qa,
                                            const f32x4 qb, const f32x4 qc) {
    const f32x4 a = pa - qa;
    const f32x4 b = pb - qb;
    const f32x4 c = pc - qc;
    float s;
    s  = sqrtf(a.x * a.x + a.y * a.y + a.z * a.z);
    s += sqrtf(a.w * a.w + b.x * b.x + b.y * b.y);
    s += sqrtf(b.z * b.z + b.w * b.w + c.x * c.x);
    s += sqrtf(c.y * c.y + c.z * c.z + c.w * c.w);
    return s;
}

// MLP-depth experiment: each thread owns exactly 3 groups (12 triples); all
// 18 nontemporal dwordx4 loads are issued before any consumption, tripling
// the per-wave outstanding-read depth vs round 4 (6 -> 18). Tests whether
// the ~3.3 TB/s read cap is per-wave (win) or per-CU MSHR (null).
__global__ __launch_bounds__(NTHREADS) void dis_partial_kernel(
    const f32x4* __restrict__ p4, const f32x4* __restrict__ t4,
    const float* __restrict__ pred, const float* __restrict__ targ,
    float* __restrict__ partials, int ngroup, int ntrip) {
    const int nth = gridDim.x * NTHREADS;
    const int tid = blockIdx.x * NTHREADS + threadIdx.x;
    float acc = 0.f;

    if (ngroup == 3 * nth) {
        // Exact-fit fast path: peel all 3 groups, 18 loads in flight.
        const int b0 = 3 * tid;
        const int b1 = 3 * (tid + nth);
        const int b2 = 3 * (tid + 2 * nth);
        const f32x4 pa0 = __builtin_nontemporal_load(&p4[b0 + 0]);
        const f32x4 pb0 = __builtin_nontemporal_load(&p4[b0 + 1]);
        const f32x4 pc0 = __builtin_nontemporal_load(&p4[b0 + 2]);
        const f32x4 qa0 = __builtin_nontemporal_load(&t4[b0 + 0]);
        const f32x4 qb0 = __builtin_nontemporal_load(&t4[b0 + 1]);
        const f32x4 qc0 = __builtin_nontemporal_load(&t4[b0 + 2]);
        const f32x4 pa1 = __builtin_nontemporal_load(&p4[b1 + 0]);
        const f32x4 pb1 = __builtin_nontemporal_load(&p4[b1 + 1]);
        const f32x4 pc1 = __builtin_nontemporal_load(&p4[b1 + 2]);
        const f32x4 qa1 = __builtin_nontemporal_load(&t4[b1 + 0]);
        const f32x4 qb1 = __builtin_nontemporal_load(&t4[b1 + 1]);
        const f32x4 qc1 = __builtin_nontemporal_load(&t4[b1 + 2]);
        const f32x4 pa2 = __builtin_nontemporal_load(&p4[b2 + 0]);
        const f32x4 pb2 = __builtin_nontemporal_load(&p4[b2 + 1]);
        const f32x4 pc2 = __builtin_nontemporal_load(&p4[b2 + 2]);
        const f32x4 qa2 = __builtin_nontemporal_load(&t4[b2 + 0]);
        const f32x4 qb2 = __builtin_nontemporal_load(&t4[b2 + 1]);
        const f32x4 qc2 = __builtin_nontemporal_load(&t4[b2 + 2]);
        acc += group_dist(pa0, pb0, pc0, qa0, qb0, qc0);
        acc += group_dist(pa1, pb1, pc1, qa1, qb1, qc1);
        acc += group_dist(pa2, pb2, pc2, qa2, qb2, qc2);
    } else {
        // Generic grid-stride fallback (not taken for B=262144).
        for (int g = tid; g < ngroup; g += nth) {
            const int b = 3 * g;
            const f32x4 pa = __builtin_nontemporal_load(&p4[b + 0]);
            const f32x4 pb = __builtin_nontemporal_load(&p4[b + 1]);
            const f32x4 pc = __builtin_nontemporal_load(&p4[b + 2]);
            const f32x4 qa = __builtin_nontemporal_load(&t4[b + 0]);
            const f32x4 qb = __builtin_nontemporal_load(&t4[b + 1]);
            const f32x4 qc = __builtin_nontemporal_load(&t4[b + 2]);
            acc += group_dist(pa, pb, pc, qa, qb, qc);
        }
    }

    // Generic scalar tail (empty here: ntrip = 5,505,024 = 4 * 1,376,256).
    for (int j = ngroup * 4 + tid; j < ntrip; j += nth) {
        const float dx = pred[3 * j + 0] - targ[3 * j + 0];
        const float dy = pred[3 * j + 1] - targ[3 * j + 1];
        const float dz = pred[3 * j + 2] - targ[3 * j + 2];
        acc += sqrtf(dx * dx + dy * dy + dz * dz);
    }

    const float s = block_reduce(acc);
    if (threadIdx.x == 0) partials[blockIdx.x] = s;
}

__global__ __launch_bounds__(NTHREADS) void dis_finalize_kernel(
    const float* __restrict__ partials, float* __restrict__ out,
    int nblocks, float scale) {
    float acc = 0.f;
    for (int i = threadIdx.x; i < nblocks; i += NTHREADS) acc += partials[i];
    const float s = block_reduce(acc);
    if (threadIdx.x == 0) out[0] = s * scale;  // full overwrite of poisoned d_out
}

extern "C" void kernel_launch(void* const* d_in, const int* in_sizes, int n_in,
                              void* d_out, int out_size, void* d_ws, size_t ws_size,
                              hipStream_t stream) {
    const float* pred = (const float*)d_in[0];
    const float* targ = (const float*)d_in[1];
    float* out = (float*)d_out;
    float* partials = (float*)d_ws;  // NBLOCKS floats, each block owns its slot

    const int n = in_sizes[0];          // B * 63 = 16,515,072 floats
    const int ntrip = n / 3;            // 5,505,024 joint distances
    const int ngroup = ntrip / 4;       // 1,376,256 groups of 4 triples (exact)
    const float scale = 1.0f / (float)ntrip;

    dis_partial_kernel<<<NBLOCKS, NTHREADS, 0, stream>>>(
        (const f32x4*)pred, (const f32x4*)targ, pred, targ, partials, ngroup, ntrip);
    dis_finalize_kernel<<<1, NTHREADS, 0, stream>>>(partials, out, NBLOCKS, scale);
}